// Round 2
// baseline (114.881 us; speedup 1.0000x reference)
//
#include <hip/hip_runtime.h>
#include <hip/hip_bf16.h>

#define B_  4
#define C_  640
#define H_  64
#define W_  64
#define G_  16          // channel groups (one wave each)
#define CPG 40          // channels per group: G_*CPG == C_
#define NT  1024

__global__ __launch_bounds__(NT) void nca_fused(
    const float* __restrict__ Ft,
    const float* __restrict__ Fwp,
    const float* __restrict__ mask,
    const float* __restrict__ cw,
    const float* __restrict__ cb,
    float* __restrict__ out)
{
    __shared__ float lds_cw[2 * C_];            // 5 KB    conv weights
    __shared__ float lds_msk[3][W_];            // 0.75 KB mask rows hm,h,hp
    __shared__ float lds_sim[G_][W_][9];        // 36 KB   sim partials
    __shared__ float lds_attn[W_][9];           // 2.25 KB masked sim -> attn (in-place)
    __shared__ float lds_red[G_][W_];           // 4 KB    lambda-dot partials
    __shared__ float lds_lamT[W_];              // Ft part of lambda dot
    __shared__ float lds_lam[W_];               // final lambda
    __shared__ __hip_bfloat16 lds_f1[C_][W_];   // 80 KB   center Fwarp row (bf16 stash)

    const int t = threadIdx.x;
    const int w = t & 63;       // lane == pixel column
    const int g = t >> 6;       // channel group == wave id

    // XCD-aware swizzle: XCD x gets 8 consecutive rows (all 4 batches).
    // n = bx + 64*by in [0,256); xcd = n&7; bijective remap.
    const int n    = blockIdx.x + gridDim.x * blockIdx.y;
    const int slot = n >> 3;
    const int h = (n & 7) * 8 + (slot & 7);
    const int b = slot >> 3;

    const int hm = (h > 0) ? (h - 1) : 0;
    const int hp = (h < H_ - 1) ? (h + 1) : (H_ - 1);
    const size_t cs = (size_t)H_ * W_;
    const int c0 = g * CPG;

    // stage conv weights + mask rows
    for (int i = t; i < 2 * C_; i += NT) lds_cw[i] = cw[i];
    if (t < 3 * W_) {
        const int r = t >> 6, col = t & 63;
        const int row = (r == 0) ? hm : ((r == 1) ? h : hp);
        lds_msk[r][col] = mask[((size_t)b * H_ + row) * W_ + col];
    }
    __syncthreads();

    const float* ftp = Ft  + ((size_t)(b * C_ + c0) * H_ + h ) * W_ + w;
    const float* f0p = Fwp + ((size_t)(b * C_ + c0) * H_ + hm) * W_ + w;
    const float* f1p = Fwp + ((size_t)(b * C_ + c0) * H_ + h ) * W_ + w;
    const float* f2p = Fwp + ((size_t)(b * C_ + c0) * H_ + hp) * W_ + w;

    // ---------------- Pass A: sim partials (displaced accumulation) --------
    float sC0=0.f, sC1=0.f, sC2=0.f;
    float sA0=0.f, sA1=0.f, sA2=0.f;
    float sB0=0.f, sB1=0.f, sB2=0.f;
    float lamT = 0.f;
    const int lnL = (w - 1) & 63;
    const int lnR = (w + 1) & 63;

    float ft[CPG];                       // kept in regs for Pass C (static idx)
    #pragma unroll
    for (int k = 0; k < CPG; ++k) {
        ft[k]    = ftp[k * cs];
        float f0 = f0p[k * cs];
        float f1 = f1p[k * cs];
        float f2 = f2p[k * cs];
        lds_f1[c0 + k][w] = __float2bfloat16(f1);     // stash center row
        float ftL = __shfl(ft[k], lnL, 64);
        float ftR = __shfl(ft[k], lnR, 64);
        sC0 = fmaf(ft[k], f0, sC0); sC1 = fmaf(ft[k], f1, sC1); sC2 = fmaf(ft[k], f2, sC2);
        sA0 = fmaf(ftR , f0, sA0); sA1 = fmaf(ftR , f1, sA1); sA2 = fmaf(ftR , f2, sA2);
        sB0 = fmaf(ftL , f0, sB0); sB1 = fmaf(ftL , f1, sB1); sB2 = fmaf(ftL , f2, sB2);
        lamT = fmaf(lds_cw[C_ + c0 + k], ft[k], lamT);
    }

    // realign displaced accumulators to the owning pixel
    float simn[9];
    simn[1] = sC0; simn[4] = sC1; simn[7] = sC2;
    simn[0] = __shfl(sA0, lnL, 64);
    simn[3] = __shfl(sA1, lnL, 64);
    simn[6] = __shfl(sA2, lnL, 64);
    simn[2] = __shfl(sB0, lnR, 64);
    simn[5] = __shfl(sB1, lnR, 64);
    simn[8] = __shfl(sB2, lnR, 64);
    if (w == 0)      { simn[0] = sC0; simn[3] = sC1; simn[6] = sC2; }  // replicate pad
    if (w == W_ - 1) { simn[2] = sC0; simn[5] = sC1; simn[8] = sC2; }

    #pragma unroll
    for (int q = 0; q < 9; ++q) lds_sim[g][w][q] = simn[q];
    lds_red[g][w] = lamT;
    __syncthreads();

    // ---------------- reduce across groups + mask --------------------------
    if (t < W_ * 9) {
        const int ww = t / 9, q = t % 9;
        float s = 0.f;
        #pragma unroll
        for (int gg = 0; gg < G_; ++gg) s += lds_sim[gg][ww][q];
        s *= 0.03952847075210474f;          // 1/sqrt(640)
        const int r = q / 3, j = q % 3;
        int col = ww + j - 1;
        col = col < 0 ? 0 : (col > W_ - 1 ? W_ - 1 : col);
        if (lds_msk[r][col] == 1.0f) s = -1e9f;
        lds_attn[ww][q] = s;                // masked sim (softmax'd in place)
    }
    __syncthreads();

    // ---------------- softmax per pixel + lamT reduce ----------------------
    if (t < W_) {
        float v[9];
        float mx = -3e38f;
        bool valid = false;
        #pragma unroll
        for (int q = 0; q < 9; ++q) {
            v[q] = lds_attn[t][q];
            if (v[q] > -5e8f) valid = true;
            mx = fmaxf(mx, v[q]);
        }
        float lt = 0.f;
        #pragma unroll
        for (int gg = 0; gg < G_; ++gg) lt += lds_red[gg][t];
        lds_lamT[t] = lt;
        if (!valid) {
            #pragma unroll
            for (int q = 0; q < 9; ++q) lds_attn[t][q] = 0.f;
        } else {
            float e[9], sum = 0.f;
            #pragma unroll
            for (int q = 0; q < 9; ++q) { e[q] = expf(v[q] - mx); sum += e[q]; }
            const float inv = 1.f / sum;
            #pragma unroll
            for (int q = 0; q < 9; ++q) lds_attn[t][q] = e[q] * inv;
        }
    }
    __syncthreads();

    // ---------------- Pass B: Fw via displaced per-source sums -------------
    // Pre-shuffled attn: SP (belongs to pixel w+1), SS (w), SM (w-1).
    // Replicate-clamp at columns 0/63 folded into the center weights.
    float aL[3], aC[3], aR[3];
    #pragma unroll
    for (int r = 0; r < 3; ++r) {
        const float a0 = lds_attn[w][3 * r];
        const float a1 = lds_attn[w][3 * r + 1];
        const float a2 = lds_attn[w][3 * r + 2];
        aC[r] = a1;
        if (w == 0)      aC[r] += a0;
        if (w == W_ - 1) aC[r] += a2;
        aL[r] = (w < W_ - 1) ? lds_attn[w + 1][3 * r]     : 0.f;
        aR[r] = (w > 0)      ? lds_attn[w - 1][3 * r + 2] : 0.f;
    }

    float fwv[CPG];
    float lamF = 0.f;
    #pragma unroll
    for (int k = 0; k < CPG; ++k) {
        float f0 = f0p[k * cs];
        float f1 = __bfloat162float(lds_f1[c0 + k][w]);
        float f2 = f2p[k * cs];
        float SP = aL[0] * f0 + aL[1] * f1 + aL[2] * f2;   // -> pixel w+1
        float SS = aC[0] * f0 + aC[1] * f1 + aC[2] * f2;   // -> pixel w
        float SM = aR[0] * f0 + aR[1] * f1 + aR[2] * f2;   // -> pixel w-1
        fwv[k] = __shfl(SP, lnL, 64) + SS + __shfl(SM, lnR, 64);
        lamF = fmaf(lds_cw[c0 + k], fwv[k], lamF);
    }
    lds_red[g][w] = lamF;
    __syncthreads();

    // ---------------- lambda = sigmoid(dot + bias) -------------------------
    if (t < W_) {
        float s = lds_lamT[t];
        #pragma unroll
        for (int gg = 0; gg < G_; ++gg) s += lds_red[gg][t];
        s += cb[0];
        lds_lam[t] = 1.f / (1.f + expf(-s));
    }
    __syncthreads();

    // ---------------- Pass C: out = lam*Ft + (1-lam)*Fw (no loads) ---------
    const float lam = lds_lam[w];
    const float oml = 1.f - lam;
    float* outp = out + ((size_t)(b * C_ + c0) * H_ + h) * W_ + w;
    #pragma unroll
    for (int k = 0; k < CPG; ++k) {
        outp[k * cs] = lam * ft[k] + oml * fwv[k];
    }
}

extern "C" void kernel_launch(void* const* d_in, const int* in_sizes, int n_in,
                              void* d_out, int out_size, void* d_ws, size_t ws_size,
                              hipStream_t stream) {
    const float* Ft   = (const float*)d_in[0];
    const float* Fwp  = (const float*)d_in[1];
    const float* mask = (const float*)d_in[2];
    const float* cw   = (const float*)d_in[3];
    const float* cb   = (const float*)d_in[4];
    float* out = (float*)d_out;

    dim3 grid(H_, B_);   // 256 blocks == 256 CUs
    dim3 block(NT);
    nca_fused<<<grid, block, 0, stream>>>(Ft, Fwp, mask, cw, cb, out);
}

// Round 3
// 52.133 us; speedup vs baseline: 2.2036x; 2.2036x over previous
//
#include <hip/hip_runtime.h>
#include <hip/hip_bf16.h>

#define B_  4
#define C_  640
#define H_  64
#define W_  64
#define G_  16          // channel groups (one wave each)
#define CPG 40          // channels per group: G_*CPG == C_
#define NT  1024

__global__ __launch_bounds__(NT, 4) void nca_fused(   // 4 waves/EU = 1 block/CU -> VGPR cap 128
    const float* __restrict__ Ft,
    const float* __restrict__ Fwp,
    const float* __restrict__ mask,
    const float* __restrict__ cw,
    const float* __restrict__ cb,
    float* __restrict__ out)
{
    __shared__ float lds_cw[2 * C_];            // 5 KB    conv weights
    __shared__ float lds_msk[3][W_];            // 0.75 KB mask rows hm,h,hp
    __shared__ float lds_sim[G_][W_][9];        // 36 KB   sim partials
    __shared__ float lds_attn[W_][9];           // 2.25 KB masked sim -> attn (in place)
    __shared__ float lds_red[G_][W_];           // 4 KB    lambda-dot partials
    __shared__ float lds_lamT[W_];              // Ft part of lambda dot
    __shared__ float lds_lam[W_];               // final lambda
    __shared__ __hip_bfloat16 lds_fw[C_][W_];   // 80 KB   weighted Fwarp (bf16)

    const int t = threadIdx.x;
    const int w = t & 63;       // lane == pixel column
    const int g = t >> 6;       // channel group == wave id

    // XCD-aware swizzle: XCD x owns 8 consecutive rows (x*8..x*8+7) for all 4
    // batches -> Fwarp row sharing stays within one L2. Bijective.
    const int n    = blockIdx.x + gridDim.x * blockIdx.y;
    const int slot = n >> 3;
    const int h = (n & 7) * 8 + (slot & 7);
    const int b = slot >> 3;

    const int hm = (h > 0) ? (h - 1) : 0;
    const int hp = (h < H_ - 1) ? (h + 1) : (H_ - 1);
    const size_t cs = (size_t)H_ * W_;
    const int c0 = g * CPG;

    // stage conv weights + mask rows
    for (int i = t; i < 2 * C_; i += NT) lds_cw[i] = cw[i];
    if (t < 3 * W_) {
        const int r = t >> 6, col = t & 63;
        const int row = (r == 0) ? hm : ((r == 1) ? h : hp);
        lds_msk[r][col] = mask[((size_t)b * H_ + row) * W_ + col];
    }
    __syncthreads();

    const float* ftp = Ft  + ((size_t)(b * C_ + c0) * H_ + h ) * W_ + w;
    const float* f0p = Fwp + ((size_t)(b * C_ + c0) * H_ + hm) * W_ + w;
    const float* f1p = Fwp + ((size_t)(b * C_ + c0) * H_ + h ) * W_ + w;
    const float* f2p = Fwp + ((size_t)(b * C_ + c0) * H_ + hp) * W_ + w;

    // ---------------- Pass A: sim partials (displaced accumulation) --------
    // sC[r]: ft[w]   * fw[r][w] -> pixel w    (dj =  0)
    // sA[r]: ft[w+1] * fw[r][w] -> pixel w+1  (dj = -1, realigned later)
    // sB[r]: ft[w-1] * fw[r][w] -> pixel w-1  (dj = +1, realigned later)
    float sC0=0.f, sC1=0.f, sC2=0.f;
    float sA0=0.f, sA1=0.f, sA2=0.f;
    float sB0=0.f, sB1=0.f, sB2=0.f;
    float lamT = 0.f;
    const int lnL = (w - 1) & 63;
    const int lnR = (w + 1) & 63;

    float ft[CPG];          // lives to Pass C; full unroll -> static indexing
    #pragma unroll
    for (int k = 0; k < CPG; ++k) {
        ft[k]    = ftp[k * cs];
        float f0 = f0p[k * cs];
        float f1 = f1p[k * cs];
        float f2 = f2p[k * cs];
        float ftL = __shfl(ft[k], lnL, 64);
        float ftR = __shfl(ft[k], lnR, 64);
        sC0 = fmaf(ft[k], f0, sC0); sC1 = fmaf(ft[k], f1, sC1); sC2 = fmaf(ft[k], f2, sC2);
        sA0 = fmaf(ftR , f0, sA0); sA1 = fmaf(ftR , f1, sA1); sA2 = fmaf(ftR , f2, sA2);
        sB0 = fmaf(ftL , f0, sB0); sB1 = fmaf(ftL , f1, sB1); sB2 = fmaf(ftL , f2, sB2);
        lamT = fmaf(lds_cw[C_ + c0 + k], ft[k], lamT);
    }

    // realign displaced accumulators to the owning pixel
    float simn[9];
    simn[1] = sC0; simn[4] = sC1; simn[7] = sC2;
    simn[0] = __shfl(sA0, lnL, 64);
    simn[3] = __shfl(sA1, lnL, 64);
    simn[6] = __shfl(sA2, lnL, 64);
    simn[2] = __shfl(sB0, lnR, 64);
    simn[5] = __shfl(sB1, lnR, 64);
    simn[8] = __shfl(sB2, lnR, 64);
    if (w == 0)      { simn[0] = sC0; simn[3] = sC1; simn[6] = sC2; }  // replicate pad
    if (w == W_ - 1) { simn[2] = sC0; simn[5] = sC1; simn[8] = sC2; }

    #pragma unroll
    for (int q = 0; q < 9; ++q) lds_sim[g][w][q] = simn[q];
    lds_red[g][w] = lamT;
    __syncthreads();

    // ---------------- reduce across groups + mask --------------------------
    if (t < W_ * 9) {
        const int ww = t / 9, q = t % 9;
        float s = 0.f;
        #pragma unroll
        for (int gg = 0; gg < G_; ++gg) s += lds_sim[gg][ww][q];
        s *= 0.03952847075210474f;          // 1/sqrt(640)
        const int r = q / 3, j = q % 3;
        int col = ww + j - 1;
        col = col < 0 ? 0 : (col > W_ - 1 ? W_ - 1 : col);
        if (lds_msk[r][col] == 1.0f) s = -1e9f;
        lds_attn[ww][q] = s;
    }
    __syncthreads();

    // ---------------- softmax per pixel + lamT reduce ----------------------
    if (t < W_) {
        float v[9];
        float mx = -3e38f;
        bool valid = false;
        #pragma unroll
        for (int q = 0; q < 9; ++q) {
            v[q] = lds_attn[t][q];
            if (v[q] > -5e8f) valid = true;
            mx = fmaxf(mx, v[q]);
        }
        float lt = 0.f;
        #pragma unroll
        for (int gg = 0; gg < G_; ++gg) lt += lds_red[gg][t];
        lds_lamT[t] = lt;
        if (!valid) {
            #pragma unroll
            for (int q = 0; q < 9; ++q) lds_attn[t][q] = 0.f;
        } else {
            float e[9], sum = 0.f;
            #pragma unroll
            for (int q = 0; q < 9; ++q) { e[q] = expf(v[q] - mx); sum += e[q]; }
            const float inv = 1.f / sum;
            #pragma unroll
            for (int q = 0; q < 9; ++q) lds_attn[t][q] = e[q] * inv;
        }
    }
    __syncthreads();

    // ---------------- Pass B: Fw via displaced per-source sums -------------
    // Re-reads f0/f1/f2 (L2-warm from Pass A). 2 shuffles per channel.
    float aL[3], aC[3], aR[3];
    #pragma unroll
    for (int r = 0; r < 3; ++r) {
        const float a0 = lds_attn[w][3 * r];
        const float a1 = lds_attn[w][3 * r + 1];
        const float a2 = lds_attn[w][3 * r + 2];
        aC[r] = a1;
        if (w == 0)      aC[r] += a0;      // replicate clamp folded into center
        if (w == W_ - 1) aC[r] += a2;
        aL[r] = (w < W_ - 1) ? lds_attn[w + 1][3 * r]     : 0.f;
        aR[r] = (w > 0)      ? lds_attn[w - 1][3 * r + 2] : 0.f;
    }

    float lamF = 0.f;
    #pragma unroll 8
    for (int k = 0; k < CPG; ++k) {
        float f0 = f0p[k * cs];
        float f1 = f1p[k * cs];
        float f2 = f2p[k * cs];
        float SP = aL[0] * f0 + aL[1] * f1 + aL[2] * f2;   // -> pixel w+1
        float SS = aC[0] * f0 + aC[1] * f1 + aC[2] * f2;   // -> pixel w
        float SM = aR[0] * f0 + aR[1] * f1 + aR[2] * f2;   // -> pixel w-1
        float fwv = __shfl(SP, lnL, 64) + SS + __shfl(SM, lnR, 64);
        lds_fw[c0 + k][w] = __float2bfloat16(fwv);
        lamF = fmaf(lds_cw[c0 + k], fwv, lamF);            // pre-rounding value
    }
    lds_red[g][w] = lamF;
    __syncthreads();

    // ---------------- lambda = sigmoid(dot + bias) -------------------------
    if (t < W_) {
        float s = lds_lamT[t];
        #pragma unroll
        for (int gg = 0; gg < G_; ++gg) s += lds_red[gg][t];
        s += cb[0];
        lds_lam[t] = 1.f / (1.f + expf(-s));
    }
    __syncthreads();

    // ---------------- Pass C: out = lam*Ft + (1-lam)*Fw (no global loads) --
    const float lam = lds_lam[w];
    const float oml = 1.f - lam;
    float* outp = out + ((size_t)(b * C_ + c0) * H_ + h) * W_ + w;
    #pragma unroll
    for (int k = 0; k < CPG; ++k) {
        const float fwv = __bfloat162float(lds_fw[c0 + k][w]);
        outp[k * cs] = lam * ft[k] + oml * fwv;
    }
}

extern "C" void kernel_launch(void* const* d_in, const int* in_sizes, int n_in,
                              void* d_out, int out_size, void* d_ws, size_t ws_size,
                              hipStream_t stream) {
    const float* Ft   = (const float*)d_in[0];
    const float* Fwp  = (const float*)d_in[1];
    const float* mask = (const float*)d_in[2];
    const float* cw   = (const float*)d_in[3];
    const float* cb   = (const float*)d_in[4];
    float* out = (float*)d_out;

    dim3 grid(H_, B_);   // 256 blocks == 256 CUs
    dim3 block(NT);
    nca_fused<<<grid, block, 0, stream>>>(Ft, Fwp, mask, cw, cb, out);
}